// Round 1
// baseline (1567.776 us; speedup 1.0000x reference)
//
#include <hip/hip_runtime.h>

// PerlinPowerFractal: B=16, H=W=1024, 8 octaves, per-image minmax normalize.
// Strategy: collapse the 3-level permutation gather chain into a per-(image,octave)
// 256x256 byte table G (lo nibble = hash@z, hi nibble = hash@z+1), then the main
// kernel does 4 byte loads + pure VALU per (pixel, octave).

#define HW  1048576       // 1024*1024
#define PSTRIDE 2097152   // 2 * P_COUNT per image

struct ZTab { float zf; float w; int Zi; int pad; };

__device__ __forceinline__ float fadef(float t) {
    return t * t * t * (t * (t * 6.0f - 15.0f) + 10.0f);
}
__device__ __forceinline__ float lerpf(float t, float a, float b) {
    return a + t * (b - a);
}
__device__ __forceinline__ float gradf(int h, float x, float y, float z) {
    float u = (h < 8) ? x : y;
    float v = (h < 4) ? y : ((h == 12 || h == 14) ? x : z);
    u = (h & 1) ? -u : u;
    v = (h & 2) ? -v : v;
    return u + v;
}
// order-preserving float<->uint maps for unsigned atomicMin/Max
__device__ __forceinline__ unsigned f2ord(float f) {
    unsigned u = __float_as_uint(f);
    return (u & 0x80000000u) ? ~u : (u | 0x80000000u);
}
__device__ __forceinline__ float ord2f(unsigned u) {
    return __uint_as_float((u & 0x80000000u) ? (u ^ 0x80000000u) : ~u);
}

// k0: per-(b,o) z scalars + minmax init. 1 block x 128 threads.
__global__ void ppf_k0(const float* __restrict__ Z, ZTab* __restrict__ zs,
                       unsigned* __restrict__ minmax) {
    int t = threadIdx.x;
    if (t < 128) {
        int b = t >> 3, o = t & 7;
        float z0 = 0.1f * (float)b + Z[0];          // EVOLUTION*b + Z + FRAME
        float freq = (float)(1 << o);
        float nz = (z0 / 100.0f) * freq;            // (z0 + 0)/SCALE * freq
        float fz = floorf(nz);
        ZTab zt;
        zt.Zi = ((int)fz) % 255;
        zt.zf = nz - fz;
        zt.w  = fadef(zt.zf);
        zt.pad = 0;
        zs[t] = zt;
    }
    if (t < 32) {
        // even index = min slot (init to max uint for atomicMin),
        // odd index  = max slot (init to 0 for atomicMax)
        minmax[t] = (t & 1) ? 0u : 0xFFFFFFFFu;
    }
}

// k1: build G[b][o][Yi][Xi] byte tables. grid(256=Yi, 16=b) x 256 threads (Xi).
__global__ void ppf_k1(const int* __restrict__ p_all, const ZTab* __restrict__ zs,
                       unsigned char* __restrict__ G) {
    int i = threadIdx.x;     // Xi
    int j = blockIdx.x;      // Yi
    int b = blockIdx.y;
    const int* p = p_all + (size_t)b * PSTRIDE;
    int pi = p[i];           // coalesced
    int q  = p[pi + j];      // gather: p[p[Xi] + Yi]
    size_t gbase = (size_t)b * 8 * 65536 + (size_t)j * 256 + i;
#pragma unroll
    for (int o = 0; o < 8; o++) {
        int Zi = zs[b * 8 + o].Zi;
        int h0 = p[q + Zi] & 15;
        int h1 = p[q + Zi + 1] & 15;
        G[gbase + (size_t)o * 65536] = (unsigned char)(h0 | (h1 << 4));
    }
}

// k2: main noise kernel. grid(4096, 16=b) x 256 threads; one pixel per thread.
__launch_bounds__(256)
__global__ void ppf_k2(const unsigned char* __restrict__ G, const ZTab* __restrict__ zs,
                       const float* __restrict__ X, const float* __restrict__ Y,
                       float* __restrict__ out, unsigned* __restrict__ minmax) {
    int tid = threadIdx.x;
    int b = blockIdx.y;
    int pixel = blockIdx.x * 256 + tid;
    int r = pixel >> 10;
    int c = pixel & 1023;
    // replicate reference op order: (coord + offset) / 100.0f, then * 2^o (exact)
    float tx = ((float)c + X[0]) / 100.0f;
    float ty = ((float)r + Y[0]) / 100.0f;
    const unsigned char* Gb = G + (size_t)b * 8 * 65536;
    float acc = 0.0f, fr = 1.0f, aw = 1.0f;
#pragma unroll
    for (int o = 0; o < 8; o++) {
        float x = tx * fr, y = ty * fr;
        float fx = floorf(x), fy = floorf(y);
        int Xi = ((int)fx) % 255;
        int Yi = ((int)fy) % 255;
        float xf = x - fx, yf = y - fy;
        float u = fadef(xf), v = fadef(yf);
        float zf = zs[b * 8 + o].zf;
        float w  = zs[b * 8 + o].w;
        const unsigned char* Go = Gb + o * 65536 + Yi * 256;
        int h00 = Go[Xi];
        int h10 = Go[Xi + 1];
        int h01 = Go[256 + Xi];
        int h11 = Go[256 + Xi + 1];
        float xm1 = xf - 1.0f, ym1 = yf - 1.0f, zm1 = zf - 1.0f;
        float g000 = gradf(h00 & 15, xf,  yf,  zf);
        float g100 = gradf(h10 & 15, xm1, yf,  zf);
        float g010 = gradf(h01 & 15, xf,  ym1, zf);
        float g110 = gradf(h11 & 15, xm1, ym1, zf);
        float g001 = gradf(h00 >> 4, xf,  yf,  zm1);
        float g101 = gradf(h10 >> 4, xm1, yf,  zm1);
        float g011 = gradf(h01 >> 4, xf,  ym1, zm1);
        float g111 = gradf(h11 >> 4, xm1, ym1, zm1);
        float x1 = lerpf(u, g000, g100);
        float x2 = lerpf(u, g010, g110);
        float x3 = lerpf(u, g001, g101);
        float x4 = lerpf(u, g011, g111);
        float n = lerpf(w, lerpf(v, x1, x2), lerpf(v, x3, x4));
        acc += n * aw;
        fr *= 2.0f;
        aw *= 0.03125f;   // 0.5^5 exact
    }
    out[(size_t)b * HW + pixel] = acc;

    // block min/max reduce -> one atomic pair per block
    float mn = acc, mx = acc;
#pragma unroll
    for (int off = 32; off > 0; off >>= 1) {
        mn = fminf(mn, __shfl_down(mn, off));
        mx = fmaxf(mx, __shfl_down(mx, off));
    }
    __shared__ float smn[4], smx[4];
    if ((tid & 63) == 0) { smn[tid >> 6] = mn; smx[tid >> 6] = mx; }
    __syncthreads();
    if (tid == 0) {
        mn = fminf(fminf(smn[0], smn[1]), fminf(smn[2], smn[3]));
        mx = fmaxf(fmaxf(smx[0], smx[1]), fmaxf(smx[2], smx[3]));
        atomicMin(&minmax[2 * b],     f2ord(mn));
        atomicMax(&minmax[2 * b + 1], f2ord(mx));
    }
}

// k3: normalize in place. grid(1024, 16=b) x 256 threads, float4.
__global__ void ppf_k3(float* __restrict__ out, const unsigned* __restrict__ minmax) {
    int b = blockIdx.y;
    int idx = blockIdx.x * 256 + threadIdx.x;
    float mn = ord2f(minmax[2 * b]);
    float mx = ord2f(minmax[2 * b + 1]);
    float s = 1.0f / (mx - mn);
    float4* o4 = (float4*)(out + (size_t)b * HW);
    float4 v = o4[idx];
    v.x = (v.x - mn) * s;
    v.y = (v.y - mn) * s;
    v.z = (v.z - mn) * s;
    v.w = (v.w - mn) * s;
    o4[idx] = v;
}

extern "C" void kernel_launch(void* const* d_in, const int* in_sizes, int n_in,
                              void* d_out, int out_size, void* d_ws, size_t ws_size,
                              hipStream_t stream) {
    const int*   p_all = (const int*)d_in[0];
    const float* X     = (const float*)d_in[1];
    const float* Y     = (const float*)d_in[2];
    const float* Z     = (const float*)d_in[3];
    float* out = (float*)d_out;

    // ws layout: G tables (8 MB) | ZTab[128] (2 KB, 16B aligned) | minmax (128 B)
    unsigned char* G   = (unsigned char*)d_ws;
    ZTab* zs           = (ZTab*)((char*)d_ws + (size_t)8 * 1024 * 1024);
    unsigned* minmax   = (unsigned*)((char*)d_ws + (size_t)8 * 1024 * 1024 + 4096);

    ppf_k0<<<1, 128, 0, stream>>>(Z, zs, minmax);
    ppf_k1<<<dim3(256, 16), 256, 0, stream>>>(p_all, zs, G);
    ppf_k2<<<dim3(4096, 16), 256, 0, stream>>>(G, zs, X, Y, out, minmax);
    ppf_k3<<<dim3(1024, 16), 256, 0, stream>>>(out, minmax);
}

// Round 2
// 569.302 us; speedup vs baseline: 2.7539x; 2.7539x over previous
//
#include <hip/hip_runtime.h>

// PerlinPowerFractal: B=16, H=W=1024, 8 octaves, per-image minmax normalize.
// R2: fold z-lerp + grad() into per-(b,o) 256-entry affine coefficient tables
//     F(byte; x, y) = A*x + CY*y + CZ  ==  (1-w)*grad(lo;x,y,zf) + w*grad(hi;x,y,zf-1)
//     and stage tables + the two needed G rows per octave in LDS. One block per
//     (row, image); y-side quantities are block-uniform.

#define HW  1048576       // 1024*1024
#define PSTRIDE 2097152   // 2 * P_COUNT per image

struct ZTab { float zf; float w; int Zi; int pad; };

__device__ __forceinline__ float fadef(float t) {
    return t * t * t * (t * (t * 6.0f - 15.0f) + 10.0f);
}
__device__ __forceinline__ unsigned f2ord(float f) {
    unsigned u = __float_as_uint(f);
    return (u & 0x80000000u) ? ~u : (u | 0x80000000u);
}
__device__ __forceinline__ float ord2f(unsigned u) {
    return __uint_as_float((u & 0x80000000u) ? (u ^ 0x80000000u) : ~u);
}

// k0: per-(b,o) z scalars + minmax init. 1 block x 128 threads.
__global__ void ppf_k0(const float* __restrict__ Z, ZTab* __restrict__ zs,
                       unsigned* __restrict__ minmax) {
    int t = threadIdx.x;
    if (t < 128) {
        int b = t >> 3, o = t & 7;
        float z0 = 0.1f * (float)b + Z[0];          // EVOLUTION*b + Z + FRAME
        float freq = (float)(1 << o);
        float nz = (z0 / 100.0f) * freq;            // (z0 + 0)/SCALE * freq
        float fz = floorf(nz);
        ZTab zt;
        zt.Zi = ((int)fz) % 255;
        zt.zf = nz - fz;
        zt.w  = fadef(zt.zf);
        zt.pad = 0;
        zs[t] = zt;
    }
    if (t < 32) {
        minmax[t] = (t & 1) ? 0u : 0xFFFFFFFFu;     // even=min slot, odd=max slot
    }
}

// k1: build G[b][o][Yi][Xi] byte tables (lo nibble=hash@Zi, hi nibble=hash@Zi+1).
// grid(256=Yi, 16=b) x 256 threads (Xi).
__global__ void ppf_k1(const int* __restrict__ p_all, const ZTab* __restrict__ zs,
                       unsigned char* __restrict__ G) {
    int i = threadIdx.x;     // Xi
    int j = blockIdx.x;      // Yi
    int b = blockIdx.y;
    const int* p = p_all + (size_t)b * PSTRIDE;
    int pi = p[i];           // coalesced
    int q  = p[pi + j];      // gather: p[p[Xi] + Yi]
    size_t gbase = (size_t)b * 8 * 65536 + (size_t)j * 256 + i;
#pragma unroll
    for (int o = 0; o < 8; o++) {
        int Zi = zs[b * 8 + o].Zi;
        int h0 = p[q + Zi] & 15;
        int h1 = p[q + Zi + 1] & 15;
        G[gbase + (size_t)o * 65536] = (unsigned char)(h0 | (h1 << 4));
    }
}

// k1b: per-(b,o) coefficient tables over the 256 byte values.
// grad(h;x,y,z) = a(h)*x + cy(h)*y + cz(h)*z with a,cy,cz in {0,+-1}; fold z-lerp:
// A = (1-w)a(lo)+w a(hi); CY likewise; CZ = (1-w)cz(lo)zf + w cz(hi)(zf-1).
// grid(8=o, 16=b) x 256 threads (byte value).
__global__ void ppf_k1b(const ZTab* __restrict__ zs,
                        float2* __restrict__ TgAB, float* __restrict__ TgCZ) {
    int beta = threadIdx.x, o = blockIdx.x, b = blockIdx.y;
    ZTab z = zs[b * 8 + o];
    float w = z.w, zf = z.zf;
    float A = 0.f, CY = 0.f, CZ = 0.f;
#pragma unroll
    for (int k = 0; k < 2; k++) {
        int   h  = k ? (beta >> 4) : (beta & 15);
        float wk = k ? w : (1.0f - w);
        float zk = k ? (zf - 1.0f) : zf;
        float s1 = (h & 1) ? -1.f : 1.f;
        float s2 = (h & 2) ? -1.f : 1.f;
        bool  vx = (h == 12) || (h == 14);          // v-term selects x
        float a  = ((h < 8) ? s1 : 0.f) + (vx ? s2 : 0.f);
        float cy = ((h >= 8) ? s1 : 0.f) + ((h < 4) ? s2 : 0.f);
        float cz = (h >= 4 && !vx) ? s2 : 0.f;
        A  = fmaf(wk, a, A);
        CY = fmaf(wk, cy, CY);
        CZ = fmaf(wk * zk, cz, CZ);
    }
    int idx = (b * 8 + o) * 256 + beta;
    TgAB[idx] = make_float2(A, CY);
    TgCZ[idx] = CZ;
}

// k2: main kernel. grid(1024=row, 16=b) x 256 threads; 4 pixels/thread (one row/block).
__launch_bounds__(256, 4)
__global__ void ppf_k2(const unsigned char* __restrict__ G,
                       const float2* __restrict__ TgAB, const float* __restrict__ TgCZ,
                       const float* __restrict__ X, const float* __restrict__ Y,
                       float* __restrict__ out, unsigned* __restrict__ minmax) {
    __shared__ float2 tAB[2048];                        // 16 KB  (A, CY per byte)
    __shared__ float  tCZ[2048];                        //  8 KB
    __shared__ __align__(16) unsigned char hrow[4096];  //  4 KB  (2 G rows x 8 octaves)
    __shared__ float smn[4], smx[4];

    const int tid = threadIdx.x;
    const int r = blockIdx.x, b = blockIdx.y;

    // stage coefficient tables (coalesced)
    const int boff = b * 2048;
#pragma unroll
    for (int j = 0; j < 8; j++) {
        int idx = tid + j * 256;
        tAB[idx] = TgAB[boff + idx];
        tCZ[idx] = TgCZ[boff + idx];
    }

    const float X0 = X[0], Y0 = Y[0];
    const float ty = ((float)r + Y0) / 100.0f;

    // stage the two G rows needed per octave: thread t -> octave t>>5, 16B chunk
    {
        int o = tid >> 5, s = tid & 31;
        float y = ty * (float)(1 << o);
        unsigned Yi = ((unsigned)(int)floorf(y)) % 255u;
        unsigned row = Yi + (unsigned)(s >> 4);
        const uint4* src = (const uint4*)(G + (((size_t)(b * 8 + o)) << 16)
                                            + row * 256u + (unsigned)(s & 15) * 16u);
        *((uint4*)(hrow + o * 512 + (s >> 4) * 256 + (s & 15) * 16)) = *src;
    }
    __syncthreads();

    float txs[4], accv[4];
#pragma unroll
    for (int i = 0; i < 4; i++) {
        txs[i] = ((float)(tid + 256 * i) + X0) / 100.0f;
        accv[i] = 0.0f;
    }

    constexpr float AW[8] = {
        1.0f, 0.03125f, 9.765625e-4f, 3.0517578125e-5f,
        9.5367431640625e-7f, 2.9802322387695312e-8f,
        9.313225746154785e-10f, 2.9103830456733704e-11f
    };

#pragma unroll
    for (int o = 0; o < 8; o++) {
        const float fr = (float)(1 << o);
        const float aw = AW[o];
        float y  = ty * fr;
        float fy = floorf(y);
        float yf = y - fy, ym1 = yf - 1.0f;     // block-uniform
        float v  = fadef(yf);
        const int hb = o * 512;
        const int tb = o * 256;
#pragma unroll
        for (int i = 0; i < 4; i++) {
            float x   = txs[i] * fr;
            float fx  = floorf(x);
            float xf  = x - fx, xm1 = xf - 1.0f;
            unsigned Xi = ((unsigned)(int)fx) % 255u;
            float u   = fadef(xf);
            int a0 = hb + (int)Xi;
            int h00 = hrow[a0], h10 = hrow[a0 + 1];
            int h01 = hrow[a0 + 256], h11 = hrow[a0 + 257];
            float2 c00 = tAB[tb + h00]; float z00 = tCZ[tb + h00];
            float2 c10 = tAB[tb + h10]; float z10 = tCZ[tb + h10];
            float2 c01 = tAB[tb + h01]; float z01 = tCZ[tb + h01];
            float2 c11 = tAB[tb + h11]; float z11 = tCZ[tb + h11];
            float F00 = fmaf(c00.x, xf,  fmaf(c00.y, yf,  z00));
            float F10 = fmaf(c10.x, xm1, fmaf(c10.y, yf,  z10));
            float F01 = fmaf(c01.x, xf,  fmaf(c01.y, ym1, z01));
            float F11 = fmaf(c11.x, xm1, fmaf(c11.y, ym1, z11));
            float P = F00 + v * (F01 - F00);
            float Q = F10 + v * (F11 - F10);
            float n = P + u * (Q - P);
            accv[i] = fmaf(n, aw, accv[i]);
        }
    }

    // store (coalesced: thread t writes pixels t, t+256, t+512, t+768 of row r)
    size_t obase = ((size_t)b << 20) + ((size_t)r << 10) + tid;
#pragma unroll
    for (int i = 0; i < 4; i++) out[obase + 256 * i] = accv[i];

    // block min/max -> one atomic pair per block
    float mn = fminf(fminf(accv[0], accv[1]), fminf(accv[2], accv[3]));
    float mx = fmaxf(fmaxf(accv[0], accv[1]), fmaxf(accv[2], accv[3]));
#pragma unroll
    for (int off = 32; off > 0; off >>= 1) {
        mn = fminf(mn, __shfl_down(mn, off));
        mx = fmaxf(mx, __shfl_down(mx, off));
    }
    if ((tid & 63) == 0) { smn[tid >> 6] = mn; smx[tid >> 6] = mx; }
    __syncthreads();
    if (tid == 0) {
        mn = fminf(fminf(smn[0], smn[1]), fminf(smn[2], smn[3]));
        mx = fmaxf(fmaxf(smx[0], smx[1]), fmaxf(smx[2], smx[3]));
        atomicMin(&minmax[2 * b],     f2ord(mn));
        atomicMax(&minmax[2 * b + 1], f2ord(mx));
    }
}

// k3: normalize in place. grid(1024, 16=b) x 256 threads, float4.
__global__ void ppf_k3(float* __restrict__ out, const unsigned* __restrict__ minmax) {
    int b = blockIdx.y;
    int idx = blockIdx.x * 256 + threadIdx.x;
    float mn = ord2f(minmax[2 * b]);
    float mx = ord2f(minmax[2 * b + 1]);
    float s = 1.0f / (mx - mn);
    float4* o4 = (float4*)(out + (size_t)b * HW);
    float4 v = o4[idx];
    v.x = (v.x - mn) * s;
    v.y = (v.y - mn) * s;
    v.z = (v.z - mn) * s;
    v.w = (v.w - mn) * s;
    o4[idx] = v;
}

extern "C" void kernel_launch(void* const* d_in, const int* in_sizes, int n_in,
                              void* d_out, int out_size, void* d_ws, size_t ws_size,
                              hipStream_t stream) {
    const int*   p_all = (const int*)d_in[0];
    const float* X     = (const float*)d_in[1];
    const float* Y     = (const float*)d_in[2];
    const float* Z     = (const float*)d_in[3];
    float* out = (float*)d_out;

    // ws layout: G (8 MB) | zs (4 KB pad) | minmax (4 KB pad) | TgAB (256 KB) | TgCZ (128 KB)
    char* ws = (char*)d_ws;
    unsigned char* G   = (unsigned char*)ws;
    ZTab*     zs       = (ZTab*)    (ws + (size_t)8 * 1024 * 1024);
    unsigned* minmax   = (unsigned*)(ws + (size_t)8 * 1024 * 1024 + 4096);
    float2*   TgAB     = (float2*)  (ws + (size_t)8 * 1024 * 1024 + 8192);
    float*    TgCZ     = (float*)   (ws + (size_t)8 * 1024 * 1024 + 8192 + 262144);

    ppf_k0<<<1, 128, 0, stream>>>(Z, zs, minmax);
    ppf_k1<<<dim3(256, 16), 256, 0, stream>>>(p_all, zs, G);
    ppf_k1b<<<dim3(8, 16), 256, 0, stream>>>(zs, TgAB, TgCZ);
    ppf_k2<<<dim3(1024, 16), 256, 0, stream>>>(G, TgAB, TgCZ, X, Y, out, minmax);
    ppf_k3<<<dim3(1024, 16), 256, 0, stream>>>(out, minmax);
}

// Round 3
// 542.412 us; speedup vs baseline: 2.8904x; 1.0496x over previous
//
#include <hip/hip_runtime.h>

// PerlinPowerFractal: B=16, H=W=1024, 8 octaves, per-image minmax normalize.
// R3: (a) per-block per-octave 256-entry COLUMN tables: fold z-lerp (per b,o) and
//     y-lerp (per block,octave) into CA,CB so the pixel loop is 2 ds_read_b64 +
//     ~20 VALU per pixel-octave (no hash gathers in the hot loop).
//     (b) pb[] = p&15 packed bytes (1MB/image, L2-resident) so k1's level-3
//     gathers stop hitting L3/HBM.

#define HW  1048576       // 1024*1024
#define PSTRIDE 2097152   // 2 * P_COUNT per image
#define PBS 1049088       // pb bytes per image (1048576+512, 16B-aligned)

struct ZTab { float zf; float w; int Zi; int pad; };

__device__ __forceinline__ float fadef(float t) {
    return t * t * t * (t * (t * 6.0f - 15.0f) + 10.0f);
}
__device__ __forceinline__ unsigned f2ord(float f) {
    unsigned u = __float_as_uint(f);
    return (u & 0x80000000u) ? ~u : (u | 0x80000000u);
}
__device__ __forceinline__ float ord2f(unsigned u) {
    return __uint_as_float((u & 0x80000000u) ? (u ^ 0x80000000u) : ~u);
}

__constant__ const float AW[8] = {
    1.0f, 0.03125f, 9.765625e-4f, 3.0517578125e-5f,
    9.5367431640625e-7f, 2.9802322387695312e-8f,
    9.313225746154785e-10f, 2.9103830456733704e-11f
};

// k0: per-(b,o) z scalars + minmax init. 1 block x 128 threads.
__global__ void ppf_k0(const float* __restrict__ Z, ZTab* __restrict__ zs,
                       unsigned* __restrict__ minmax) {
    int t = threadIdx.x;
    if (t < 128) {
        int b = t >> 3, o = t & 7;
        float z0 = 0.1f * (float)b + Z[0];          // EVOLUTION*b + Z + FRAME
        float freq = (float)(1 << o);
        float nz = (z0 / 100.0f) * freq;
        float fz = floorf(nz);
        ZTab zt;
        zt.Zi = ((int)fz) % 255;
        zt.zf = nz - fz;
        zt.w  = fadef(zt.zf);
        zt.pad = 0;
        zs[t] = zt;
    }
    if (t < 32) {
        minmax[t] = (t & 1) ? 0u : 0xFFFFFFFFu;     // even=min, odd=max
    }
}

// k0b: pb[b][k] = p[k] & 15 (bytes). grid(1025, 16) x 256; 4 ints/thread.
__global__ void ppf_k0b(const int* __restrict__ p_all, unsigned char* __restrict__ pb) {
    int idx = blockIdx.x * 256 + threadIdx.x;
    int b = blockIdx.y;
    if (idx < PBS / 4) {
        int4 v = ((const int4*)(p_all + (size_t)b * PSTRIDE))[idx];
        uchar4 o;
        o.x = (unsigned char)(v.x & 15);
        o.y = (unsigned char)(v.y & 15);
        o.z = (unsigned char)(v.z & 15);
        o.w = (unsigned char)(v.w & 15);
        ((uchar4*)(pb + (size_t)b * PBS))[idx] = o;
    }
}

// k1: build G[b][o][Yi][Xi] (lo nibble=hash@Zi, hi=hash@Zi+1). grid(256=Yi,16=b) x 256 (Xi).
template <int USE_PB>
__global__ void ppf_k1(const int* __restrict__ p_all, const unsigned char* __restrict__ pb,
                       const ZTab* __restrict__ zs, unsigned char* __restrict__ G) {
    int i = threadIdx.x;     // Xi
    int j = blockIdx.x;      // Yi
    int b = blockIdx.y;
    const int* p = p_all + (size_t)b * PSTRIDE;
    const unsigned char* pbb = pb + (size_t)b * PBS;
    int pi = p[i];           // coalesced
    int q  = p[pi + j];      // random 4B gather (L3)
    size_t gbase = (size_t)b * 8 * 65536 + (size_t)j * 256 + i;
#pragma unroll
    for (int o = 0; o < 8; o++) {
        int Zi = zs[b * 8 + o].Zi;
        int h0, h1;
        if (USE_PB) {
            h0 = pbb[q + Zi];            // adjacent bytes, L2-resident region
            h1 = pbb[q + Zi + 1];
        } else {
            h0 = p[q + Zi] & 15;
            h1 = p[q + Zi + 1] & 15;
        }
        G[gbase + (size_t)o * 65536] = (unsigned char)(h0 | (h1 << 4));
    }
}

// k1b: per-(b,o) 256-entry float4 coef table: grad folded with z-lerp.
// F(byte; x,y) = A*x + CY*y + CZ. grid(8=o, 16=b) x 256 (byte value).
__global__ void ppf_k1b(const ZTab* __restrict__ zs, float4* __restrict__ TgF4) {
    int beta = threadIdx.x, o = blockIdx.x, b = blockIdx.y;
    ZTab z = zs[b * 8 + o];
    float w = z.w, zf = z.zf;
    float A = 0.f, CY = 0.f, CZ = 0.f;
#pragma unroll
    for (int k = 0; k < 2; k++) {
        int   h  = k ? (beta >> 4) : (beta & 15);
        float wk = k ? w : (1.0f - w);
        float zk = k ? (zf - 1.0f) : zf;
        float s1 = (h & 1) ? -1.f : 1.f;
        float s2 = (h & 2) ? -1.f : 1.f;
        bool  vx = (h == 12) || (h == 14);
        float a  = ((h < 8) ? s1 : 0.f) + (vx ? s2 : 0.f);
        float cy = ((h >= 8) ? s1 : 0.f) + ((h < 4) ? s2 : 0.f);
        float cz = (h >= 4 && !vx) ? s2 : 0.f;
        A  = fmaf(wk, a, A);
        CY = fmaf(wk, cy, CY);
        CZ = fmaf(wk * zk, cz, CZ);
    }
    TgF4[(b * 8 + o) * 256 + beta] = make_float4(A, CY, CZ, 0.f);
}

// k2: main kernel. grid(1024=row, 16=b) x 256 threads; 4 pixels/thread.
// LDS: hrow 4KB + CT 16KB = 20480 B -> 8 blocks/CU.
__launch_bounds__(256, 8)
__global__ void ppf_k2(const unsigned char* __restrict__ G,
                       const float4* __restrict__ TgF4,
                       const float* __restrict__ X, const float* __restrict__ Y,
                       float* __restrict__ out, unsigned* __restrict__ minmax) {
    __shared__ __align__(16) unsigned char hrow[4096];  // 2 G rows x 8 octaves
    __shared__ float2 CT[2048];                         // [o][col]: (CA*aw, CB*aw)

    const int tid = threadIdx.x;
    const int r = blockIdx.x, b = blockIdx.y;
    const float X0 = X[0], Y0 = Y[0];
    const float ty = ((float)r + Y0) / 100.0f;

    // stage the two G rows per octave: thread t -> octave t>>5, 16B chunk
    {
        int o = tid >> 5, s = tid & 31;
        float y = ty * (float)(1 << o);
        unsigned Yi = ((unsigned)(int)floorf(y)) % 255u;
        unsigned row = Yi + (unsigned)(s >> 4);
        const uint4* src = (const uint4*)(G + (((size_t)(b * 8 + o)) << 16)
                                            + row * 256u + (unsigned)(s & 15) * 16u);
        *((uint4*)(hrow + o * 512 + (s >> 4) * 256 + (s & 15) * 16)) = *src;
    }
    __syncthreads();

    // build column tables: thread = column c, loop octaves.
    // P(col c; x) = lerp(v, F(h0; x, yf), F(h1; x, ym1)) = CA*x + CB, scaled by aw.
#pragma unroll
    for (int o = 0; o < 8; o++) {
        float y  = ty * (float)(1 << o);
        float fy = floorf(y);
        float yf = y - fy, ym1 = yf - 1.0f;
        float v  = fadef(yf);
        int h0 = hrow[o * 512 + tid];
        int h1 = hrow[o * 512 + 256 + tid];
        const float4* tg = TgF4 + ((b * 8 + o) << 8);
        float4 g0 = tg[h0];
        float4 g1 = tg[h1];
        float CA = g0.x + v * (g1.x - g0.x);
        float B0 = fmaf(g0.y, yf,  g0.z);
        float B1 = fmaf(g1.y, ym1, g1.z);
        float CB = B0 + v * (B1 - B0);
        float aw = AW[o];
        CT[o * 256 + tid] = make_float2(CA * aw, CB * aw);
    }
    __syncthreads();

    float txs[4], accv[4];
#pragma unroll
    for (int i = 0; i < 4; i++) {
        txs[i] = ((float)(tid + 256 * i) + X0) / 100.0f;
        accv[i] = 0.0f;
    }

#pragma unroll
    for (int o = 0; o < 8; o++) {
        const float fr = (float)(1 << o);
        const float2* cto = CT + o * 256;
#pragma unroll
        for (int i = 0; i < 4; i++) {
            float x   = txs[i] * fr;
            float fx  = floorf(x);
            float xf  = x - fx, xm1 = xf - 1.0f;
            unsigned Xi = ((unsigned)(int)fx) % 255u;
            float u   = fadef(xf);
            float2 c0 = cto[Xi];
            float2 c1 = cto[Xi + 1];
            float P = fmaf(c0.x, xf,  c0.y);
            float Q = fmaf(c1.x, xm1, c1.y);
            accv[i] += fmaf(u, Q - P, P);   // += aw * noise
        }
    }

    // store (coalesced: thread t writes pixels t, t+256, t+512, t+768 of row r)
    size_t obase = ((size_t)b << 20) + ((size_t)r << 10) + tid;
#pragma unroll
    for (int i = 0; i < 4; i++) out[obase + 256 * i] = accv[i];

    // block min/max -> one atomic pair per block (reuse hrow space for slots)
    float* smn = (float*)hrow;      // hrow dead after CT build (barrier passed)
    float* smx = smn + 4;
    float mn = fminf(fminf(accv[0], accv[1]), fminf(accv[2], accv[3]));
    float mx = fmaxf(fmaxf(accv[0], accv[1]), fmaxf(accv[2], accv[3]));
#pragma unroll
    for (int off = 32; off > 0; off >>= 1) {
        mn = fminf(mn, __shfl_down(mn, off));
        mx = fmaxf(mx, __shfl_down(mx, off));
    }
    if ((tid & 63) == 0) { smn[tid >> 6] = mn; smx[tid >> 6] = mx; }
    __syncthreads();
    if (tid == 0) {
        mn = fminf(fminf(smn[0], smn[1]), fminf(smn[2], smn[3]));
        mx = fmaxf(fmaxf(smx[0], smx[1]), fmaxf(smx[2], smx[3]));
        atomicMin(&minmax[2 * b],     f2ord(mn));
        atomicMax(&minmax[2 * b + 1], f2ord(mx));
    }
}

// k3: normalize in place. grid(1024, 16=b) x 256 threads, float4.
__global__ void ppf_k3(float* __restrict__ out, const unsigned* __restrict__ minmax) {
    int b = blockIdx.y;
    int idx = blockIdx.x * 256 + threadIdx.x;
    float mn = ord2f(minmax[2 * b]);
    float mx = ord2f(minmax[2 * b + 1]);
    float s = 1.0f / (mx - mn);
    float4* o4 = (float4*)(out + (size_t)b * HW);
    float4 v = o4[idx];
    v.x = (v.x - mn) * s;
    v.y = (v.y - mn) * s;
    v.z = (v.z - mn) * s;
    v.w = (v.w - mn) * s;
    o4[idx] = v;
}

extern "C" void kernel_launch(void* const* d_in, const int* in_sizes, int n_in,
                              void* d_out, int out_size, void* d_ws, size_t ws_size,
                              hipStream_t stream) {
    const int*   p_all = (const int*)d_in[0];
    const float* X     = (const float*)d_in[1];
    const float* Y     = (const float*)d_in[2];
    const float* Z     = (const float*)d_in[3];
    float* out = (float*)d_out;
    char* ws = (char*)d_ws;

    // full layout: G 8MB | pb 16*PBS | zs 4KB | mm 4KB | TgF4 512KB
    const size_t OFF_PB = 8388608;
    const size_t OFF_ZS_FULL = OFF_PB + (size_t)16 * PBS;          // 25174016
    const size_t NEED_FULL   = OFF_ZS_FULL + 8192 + 524288;
    // fallback layout (no pb): G 8MB | zs 4KB | mm 4KB | TgF4 512KB
    bool full = (ws_size >= NEED_FULL);
    size_t off_zs = full ? OFF_ZS_FULL : OFF_PB;

    unsigned char* G  = (unsigned char*)ws;
    unsigned char* pb = (unsigned char*)(ws + OFF_PB);
    ZTab*     zs      = (ZTab*)    (ws + off_zs);
    unsigned* minmax  = (unsigned*)(ws + off_zs + 4096);
    float4*   TgF4    = (float4*)  (ws + off_zs + 8192);

    ppf_k0<<<1, 128, 0, stream>>>(Z, zs, minmax);
    if (full) {
        ppf_k0b<<<dim3(1025, 16), 256, 0, stream>>>(p_all, pb);
        ppf_k1<1><<<dim3(256, 16), 256, 0, stream>>>(p_all, pb, zs, G);
    } else {
        ppf_k1<0><<<dim3(256, 16), 256, 0, stream>>>(p_all, pb, zs, G);
    }
    ppf_k1b<<<dim3(8, 16), 256, 0, stream>>>(zs, TgF4);
    ppf_k2<<<dim3(1024, 16), 256, 0, stream>>>(G, TgF4, X, Y, out, minmax);
    ppf_k3<<<dim3(1024, 16), 256, 0, stream>>>(out, minmax);
}